// Round 1
// baseline (148.728 us; speedup 1.0000x reference)
//
#include <hip/hip_runtime.h>

typedef __bf16 bf16x8 __attribute__((ext_vector_type(8)));
typedef float  f32x16 __attribute__((ext_vector_type(16)));

// fp32 -> bf16 bits, round-to-nearest-even
__device__ __forceinline__ unsigned short f2bf_bits(float f) {
    unsigned int u = __builtin_bit_cast(unsigned int, f);
    u += 0x7FFFu + ((u >> 16) & 1u);
    return (unsigned short)(u >> 16);
}

// One workgroup = one channel c, 4 batches (one per wave).
// Each wave computes the full 64x64 output of its (b,c) image.
// Out[ho,wo] = sum_r sum_kw  Weff[25+r-ho, kw] * Xp_r[wo+kw]   (Xp = row padded by 25)
// MFMA mapping per input row r: D[m=ho][n=wo] += A[m][kw] * B[kw][n]
//   A[m][kw] = Weff[25+r-ho0-m][kw]  (reversed rows, zero-padded, staged in LDS)
//   B[kw][n] = Xp_r[n + kw]          (Toeplitz; 8 shift-copies in LDS for 16B-aligned reads)
__global__ void __launch_bounds__(256) dw5_51_kernel(
    const float* __restrict__ x,
    const float* __restrict__ w5,
    const float* __restrict__ w51,
    float* __restrict__ out)
{
    // weights: 128 rows x pitch 72 elems (144 B) -> row-stride 9 slots mod 8 = conflict-free
    __shared__ unsigned short wlds[128 * 72];          // 18432 B
    // row buffers: 4 waves x 2 phases x 8 copies x 136 elems (272 B stride)
    __shared__ unsigned short rowbuf[4][2][1088];      // 17408 B

    const int tid = threadIdx.x;
    const int wg  = blockIdx.x;
    const int c   = wg >> 3;      // 0..191
    const int bg  = wg & 7;       // 0..7

    // ---- stage reversed+padded effective weights into LDS ----
    // LDS row s holds Weff row kh = 88 - s (valid kh in [0,51)), cols kw in [0,64) (pad>=51 zero)
    {
        const int s    = tid >> 1;          // 0..127
        const int half = tid & 1;
        const int kh   = 88 - s;
        const bool rowok = (kh >= 0) && (kh <= 50);
        #pragma unroll
        for (int j = 0; j < 32; ++j) {
            const int kw = half * 32 + j;
            float v = 0.0f;
            if (rowok && kw <= 50) {
                v = w51[c * 2601 + kh * 51 + kw];
                if (kh >= 23 && kh < 28 && kw >= 23 && kw < 28)
                    v += w5[c * 25 + (kh - 23) * 5 + (kw - 23)];
            }
            wlds[s * 72 + kw] = f2bf_bits(v);
        }
    }

    const int lane = tid & 63;
    const int wv   = tid >> 6;        // wave id 0..3
    const int b    = bg * 4 + wv;     // batch 0..31
    const int n32  = lane & 31;       // MFMA row/col lane index
    const int gg   = lane >> 5;       // k-group
    const int q    = lane & 7;        // shift-copy selector for B reads
    const int u8   = n32 >> 3;

    // zero this wave's row buffers (pad regions must be 0; data region rewritten every r)
    {
        unsigned int* z = (unsigned int*)&rowbuf[wv][0][0];
        #pragma unroll
        for (int i = 0; i < 17; ++i) z[lane + 64 * i] = 0u;   // 17*64 = 1088 dwords = 4352 B
    }
    __syncthreads();

    const long imgbase = ((long)b * 192 + c) * 4096;
    const float* xrow = x + imgbase + lane;
    float* outp = out + imgbase;

    // B-read base (elem units): copy q at 136*q, + 8*u8 + 8*gg ; +16*ks +32*nt as immediates
    const int bidx = 136 * q + 8 * u8 + 8 * gg;
    unsigned short* rb0 = &rowbuf[wv][0][0];
    unsigned short* rb1 = &rowbuf[wv][1][0];
    const int wbase = lane + 25;   // write position: elem = wbase + 135*qq  (copy_q[t] = Xp[t+q])

    f32x16 acc00 = {}, acc01 = {}, acc10 = {}, acc11 = {};

    // prologue: row 0 -> buf0, prefetch row 1
    float xv = xrow[0];
    {
        const unsigned short xb = f2bf_bits(xv);
        #pragma unroll
        for (int qq = 0; qq < 8; ++qq) rb0[wbase + 135 * qq] = xb;
    }
    xv = xrow[64];

    #pragma unroll 1
    for (int rr = 0; rr < 64; rr += 2) {
        // ---- phase 0: write row rr+1 -> buf1, compute row rr from buf0 ----
        {
            const unsigned short xb = f2bf_bits(xv);
            #pragma unroll
            for (int qq = 0; qq < 8; ++qq) rb1[wbase + 135 * qq] = xb;
            if (rr + 2 < 64) xv = xrow[(rr + 2) * 64];

            bf16x8 Bf[4][2];
            #pragma unroll
            for (int ks = 0; ks < 4; ++ks) {
                Bf[ks][0] = *(const bf16x8*)&rb0[bidx + 16 * ks];
                Bf[ks][1] = *(const bf16x8*)&rb0[bidx + 16 * ks + 32];
            }
            if (rr <= 56) {              // m-tile 0 (ho 0..31) active
                const int srb = (63 - rr + n32) * 72 + 8 * gg;
                #pragma unroll
                for (int ks = 0; ks < 4; ++ks) {
                    const bf16x8 Af = *(const bf16x8*)&wlds[srb + 16 * ks];
                    acc00 = __builtin_amdgcn_mfma_f32_32x32x16_bf16(Af, Bf[ks][0], acc00, 0, 0, 0);
                    acc01 = __builtin_amdgcn_mfma_f32_32x32x16_bf16(Af, Bf[ks][1], acc01, 0, 0, 0);
                }
            }
            if (rr >= 7) {               // m-tile 1 (ho 32..63) active
                const int srb = (95 - rr + n32) * 72 + 8 * gg;
                #pragma unroll
                for (int ks = 0; ks < 4; ++ks) {
                    const bf16x8 Af = *(const bf16x8*)&wlds[srb + 16 * ks];
                    acc10 = __builtin_amdgcn_mfma_f32_32x32x16_bf16(Af, Bf[ks][0], acc10, 0, 0, 0);
                    acc11 = __builtin_amdgcn_mfma_f32_32x32x16_bf16(Af, Bf[ks][1], acc11, 0, 0, 0);
                }
            }
        }
        // ---- phase 1: write row rr+2 -> buf0, compute row rr+1 from buf1 ----
        {
            const int r1 = rr + 1;
            if (rr + 2 < 64) {
                const unsigned short xb = f2bf_bits(xv);
                #pragma unroll
                for (int qq = 0; qq < 8; ++qq) rb0[wbase + 135 * qq] = xb;
                if (rr + 3 < 64) xv = xrow[(rr + 3) * 64];
            }
            bf16x8 Bf[4][2];
            #pragma unroll
            for (int ks = 0; ks < 4; ++ks) {
                Bf[ks][0] = *(const bf16x8*)&rb1[bidx + 16 * ks];
                Bf[ks][1] = *(const bf16x8*)&rb1[bidx + 16 * ks + 32];
            }
            if (r1 <= 56) {
                const int srb = (63 - r1 + n32) * 72 + 8 * gg;
                #pragma unroll
                for (int ks = 0; ks < 4; ++ks) {
                    const bf16x8 Af = *(const bf16x8*)&wlds[srb + 16 * ks];
                    acc00 = __builtin_amdgcn_mfma_f32_32x32x16_bf16(Af, Bf[ks][0], acc00, 0, 0, 0);
                    acc01 = __builtin_amdgcn_mfma_f32_32x32x16_bf16(Af, Bf[ks][1], acc01, 0, 0, 0);
                }
            }
            if (r1 >= 7) {
                const int srb = (95 - r1 + n32) * 72 + 8 * gg;
                #pragma unroll
                for (int ks = 0; ks < 4; ++ks) {
                    const bf16x8 Af = *(const bf16x8*)&wlds[srb + 16 * ks];
                    acc10 = __builtin_amdgcn_mfma_f32_32x32x16_bf16(Af, Bf[ks][0], acc10, 0, 0, 0);
                    acc11 = __builtin_amdgcn_mfma_f32_32x32x16_bf16(Af, Bf[ks][1], acc11, 0, 0, 0);
                }
            }
        }
    }

    // ---- epilogue: D layout (32x32): col = lane&31, row = (v&3) + 8*(v>>2) + 4*(lane>>5) ----
    #pragma unroll
    for (int v = 0; v < 16; ++v) {
        const int ho = (v & 3) + 8 * (v >> 2) + 4 * gg;
        outp[ho * 64 + n32]             = acc00[v];
        outp[ho * 64 + n32 + 32]        = acc01[v];
        outp[(ho + 32) * 64 + n32]      = acc10[v];
        outp[(ho + 32) * 64 + n32 + 32] = acc11[v];
    }
}

extern "C" void kernel_launch(void* const* d_in, const int* in_sizes, int n_in,
                              void* d_out, int out_size, void* d_ws, size_t ws_size,
                              hipStream_t stream) {
    (void)in_sizes; (void)n_in; (void)d_ws; (void)ws_size; (void)out_size;
    const float* x   = (const float*)d_in[0];
    const float* w5  = (const float*)d_in[1];
    const float* w51 = (const float*)d_in[2];
    float* out = (float*)d_out;
    dim3 grid(192 * 8), block(256);
    hipLaunchKernelGGL(dw5_51_kernel, grid, block, 0, stream, x, w5, w51, out);
}

// Round 2
// 141.707 us; speedup vs baseline: 1.0495x; 1.0495x over previous
//
#include <hip/hip_runtime.h>

typedef __bf16 bf16x8 __attribute__((ext_vector_type(8)));
typedef float  f32x16 __attribute__((ext_vector_type(16)));

// fp32 -> bf16 bits, round-to-nearest-even
__device__ __forceinline__ unsigned short f2bf_bits(float f) {
    unsigned int u = __builtin_bit_cast(unsigned int, f);
    u += 0x7FFFu + ((u >> 16) & 1u);
    return (unsigned short)(u >> 16);
}

// One workgroup = one channel c, 8 batches (one per wave), grid 192*4 = 768 = 3 blocks/CU even.
// Out[ho,wo] = sum_r sum_kw  Weff[25+r-ho, kw] * Xp_r[wo+kw]   (Xp = row padded by 25)
// Per input row r: D[m=ho][n=wo] += A[m][kw] * B[kw][n]
//   A[m][kw] = Weff[25+r-ho0-m][kw]  -> granule-major LDS: [g=kw/8][row] so lanes read stride-16B
//   B[kw][n] = Xp_r[n+kw]            -> 8 shift-copies (272B stride) for aligned ds_read_b128
__global__ void __launch_bounds__(512) dw5_51_kernel(
    const float* __restrict__ x,
    const float* __restrict__ w5,
    const float* __restrict__ w51,
    float* __restrict__ out)
{
    // weights, granule-major: granule g (kw/8) x 128 rows x 8 elems -> A-reads lane-stride 16B
    __shared__ unsigned short wlds[8 * 1024];          // 16384 B
    // row buffers: 8 waves x 2 phases x 8 shift-copies x 136 elems (272 B stride)
    __shared__ unsigned short rowbuf[8][2][1088];      // 34816 B   (total 51200 B -> 3 blocks/CU)

    const int tid = threadIdx.x;
    const int wg  = blockIdx.x;
    const int c   = wg >> 2;      // 0..191
    const int bg  = wg & 3;       // 0..3

    // ---- stage effective weights, reversed rows, granule-major ----
    // LDS row s holds Weff row kh = 88 - s (valid kh in [0,51)); elem kw at wlds[(kw>>3)*1024 + s*8 + (kw&7)]
    {
        const int s   = tid >> 2;           // 0..127
        const int qtr = tid & 3;
        const int kh  = 88 - s;
        const bool rowok = (kh >= 0) && (kh <= 50);
        #pragma unroll
        for (int i = 0; i < 16; ++i) {
            const int kw = qtr * 16 + i;
            float v = 0.0f;
            if (rowok && kw <= 50) {
                v = w51[c * 2601 + kh * 51 + kw];
                if (kh >= 23 && kh < 28 && kw >= 23 && kw < 28)
                    v += w5[c * 25 + (kh - 23) * 5 + (kw - 23)];
            }
            wlds[(kw >> 3) * 1024 + s * 8 + (kw & 7)] = f2bf_bits(v);
        }
    }

    const int lane = tid & 63;
    const int wv   = tid >> 6;        // wave id 0..7
    const int b    = bg * 8 + wv;     // batch 0..31
    const int n32  = lane & 31;       // MFMA m/n lane index
    const int gg   = lane >> 5;       // k-group
    const int q    = lane & 7;        // shift-copy selector for B reads
    const int u8   = n32 >> 3;

    // zero this wave's row buffers (pad regions must be 0; data region rewritten every r)
    {
        unsigned int* z = (unsigned int*)&rowbuf[wv][0][0];
        #pragma unroll
        for (int i = 0; i < 17; ++i) z[lane + 64 * i] = 0u;   // 1088 dwords = 4352 B
    }
    __syncthreads();

    const long imgbase = ((long)b * 192 + c) * 4096;
    const float* xrow = x + imgbase + lane;
    float* outp = out + imgbase;

    // B-read base (elem units): copy q at 136*q + 8*u8 + 8*gg; +16*t immediates, t=0..5
    // (dedup: old Bf[ks][nt] == d[ks + 2*nt])
    const int bidx = 136 * q + 8 * u8 + 8 * gg;
    unsigned short* rb0 = &rowbuf[wv][0][0];
    unsigned short* rb1 = &rowbuf[wv][1][0];
    const int wbase = lane + 25;   // write elem = wbase + 135*qq  (copy_q[slot s] = Xp[s+q])

    f32x16 acc00 = {}, acc01 = {}, acc10 = {}, acc11 = {};

    const int abase = gg * 1024 + n32 * 8;   // + row*8 + ks*2048

    auto compute = [&](const unsigned short* __restrict__ rb, int r) {
        bf16x8 d[6];
        #pragma unroll
        for (int t = 0; t < 6; ++t) d[t] = *(const bf16x8*)&rb[bidx + 16 * t];
        if (r <= 56) {               // m-tile 0 (ho 0..31) active
            const int ai = abase + (63 - r) * 8;
            #pragma unroll
            for (int ks = 0; ks < 4; ++ks) {
                const bf16x8 Af = *(const bf16x8*)&wlds[ai + ks * 2048];
                acc00 = __builtin_amdgcn_mfma_f32_32x32x16_bf16(Af, d[ks],     acc00, 0, 0, 0);
                acc01 = __builtin_amdgcn_mfma_f32_32x32x16_bf16(Af, d[ks + 2], acc01, 0, 0, 0);
            }
        }
        if (r >= 7) {                // m-tile 1 (ho 32..63) active
            const int ai = abase + (95 - r) * 8;
            #pragma unroll
            for (int ks = 0; ks < 4; ++ks) {
                const bf16x8 Af = *(const bf16x8*)&wlds[ai + ks * 2048];
                acc10 = __builtin_amdgcn_mfma_f32_32x32x16_bf16(Af, d[ks],     acc10, 0, 0, 0);
                acc11 = __builtin_amdgcn_mfma_f32_32x32x16_bf16(Af, d[ks + 2], acc11, 0, 0, 0);
            }
        }
    };

    // prologue: row 0 -> buf0, prefetch row 1
    float xv = xrow[0];
    {
        const unsigned short xb = f2bf_bits(xv);
        #pragma unroll
        for (int qq = 0; qq < 8; ++qq) rb0[wbase + 135 * qq] = xb;
    }
    xv = xrow[64];

    #pragma unroll 1
    for (int rr = 0; rr < 64; rr += 2) {
        // ---- phase 0: write row rr+1 -> buf1, compute row rr from buf0 ----
        {
            const unsigned short xb = f2bf_bits(xv);
            #pragma unroll
            for (int qq = 0; qq < 8; ++qq) rb1[wbase + 135 * qq] = xb;
            if (rr + 2 < 64) xv = xrow[(rr + 2) * 64];
            compute(rb0, rr);
        }
        // ---- phase 1: write row rr+2 -> buf0, compute row rr+1 from buf1 ----
        {
            if (rr + 2 < 64) {
                const unsigned short xb = f2bf_bits(xv);
                #pragma unroll
                for (int qq = 0; qq < 8; ++qq) rb0[wbase + 135 * qq] = xb;
                if (rr + 3 < 64) xv = xrow[(rr + 3) * 64];
            }
            compute(rb1, rr + 1);
        }
    }

    // ---- epilogue: D layout (32x32): col = lane&31, row = (v&3) + 8*(v>>2) + 4*(lane>>5) ----
    #pragma unroll
    for (int v = 0; v < 16; ++v) {
        const int ho = (v & 3) + 8 * (v >> 2) + 4 * gg;
        outp[ho * 64 + n32]             = acc00[v];
        outp[ho * 64 + n32 + 32]        = acc01[v];
        outp[(ho + 32) * 64 + n32]      = acc10[v];
        outp[(ho + 32) * 64 + n32 + 32] = acc11[v];
    }
}

extern "C" void kernel_launch(void* const* d_in, const int* in_sizes, int n_in,
                              void* d_out, int out_size, void* d_ws, size_t ws_size,
                              hipStream_t stream) {
    (void)in_sizes; (void)n_in; (void)d_ws; (void)ws_size; (void)out_size;
    const float* x   = (const float*)d_in[0];
    const float* w5  = (const float*)d_in[1];
    const float* w51 = (const float*)d_in[2];
    float* out = (float*)d_out;
    dim3 grid(192 * 4), block(512);
    hipLaunchKernelGGL(dw5_51_kernel, grid, block, 0, stream, x, w5, w51, out);
}

// Round 3
// 138.102 us; speedup vs baseline: 1.0769x; 1.0261x over previous
//
#include <hip/hip_runtime.h>

typedef __bf16 bf16x8 __attribute__((ext_vector_type(8)));
typedef float  f32x16 __attribute__((ext_vector_type(16)));

// fp32 -> bf16 bits, round-to-nearest-even
__device__ __forceinline__ unsigned short f2bf_bits(float f) {
    unsigned int u = __builtin_bit_cast(unsigned int, f);
    u += 0x7FFFu + ((u >> 16) & 1u);
    return (unsigned short)(u >> 16);
}

// One workgroup = one channel c, 8 images (2 per wave, 4 waves). grid = 192*4 = 768.
// Out[ho,wo] = sum_r sum_kw  Weff[25+r-ho, kw] * Xp_r[wo+kw]   (Xp = row padded by 25)
// Per input row r: D[m=ho][n=wo] += A[m][kw] * B[kw][n]
//   A[m][kw] = Weff[25+r-ho0-m][kw]  (granule-major LDS, shared across BOTH images -> half A traffic/MFMA)
//   B[kw][n] = Xp_r[n+kw]            (8 shift-copies, 272B stride, aligned ds_read_b128)
__global__ void __launch_bounds__(256, 2) dw5_51_kernel(
    const float* __restrict__ x,
    const float* __restrict__ w5,
    const float* __restrict__ w51,
    float* __restrict__ out)
{
    // weights, granule-major: g=kw/8 (8) x 128 rows x 8 elems
    __shared__ unsigned short wlds[8 * 1024];             // 16384 B
    // row buffers: 4 waves x 2 imgs x 2 phases x (8 copies x 136 elems)
    __shared__ unsigned short rowbuf[4][2][2][1088];      // 34816 B  (total 51200 B)

    const int tid = threadIdx.x;
    const int wg  = blockIdx.x;
    const int c   = wg >> 2;      // 0..191
    const int bg  = wg & 3;       // 0..3

    // ---- stage effective weights, reversed rows, granule-major ----
    // LDS row s holds Weff row kh = 88 - s; elem kw at wlds[(kw>>3)*1024 + s*8 + (kw&7)]
    {
        const int s    = tid >> 1;          // 0..127
        const int half = tid & 1;
        const int kh   = 88 - s;
        const bool rowok = (kh >= 0) && (kh <= 50);
        #pragma unroll
        for (int j = 0; j < 32; ++j) {
            const int kw = half * 32 + j;
            float v = 0.0f;
            if (rowok && kw <= 50) {
                v = w51[c * 2601 + kh * 51 + kw];
                if (kh >= 23 && kh < 28 && kw >= 23 && kw < 28)
                    v += w5[c * 25 + (kh - 23) * 5 + (kw - 23)];
            }
            wlds[(kw >> 3) * 1024 + s * 8 + (kw & 7)] = f2bf_bits(v);
        }
    }

    const int lane = tid & 63;
    const int wv   = tid >> 6;        // wave 0..3
    const int b0   = bg * 8 + wv * 2; // first image batch index
    const int n32  = lane & 31;
    const int gg   = lane >> 5;
    const int q    = lane & 7;
    const int u8   = n32 >> 3;

    // zero this wave's row buffers (2 imgs x 2 phases x 2176 B = 8704 B)
    {
        unsigned int* z = (unsigned int*)&rowbuf[wv][0][0][0];
        #pragma unroll
        for (int i = 0; i < 34; ++i) z[lane + 64 * i] = 0u;
    }
    __syncthreads();

    const long ib0 = ((long)b0 * 192 + c) * 4096;
    const long ib1 = ((long)(b0 + 1) * 192 + c) * 4096;
    const float* xr0 = x + ib0 + lane;
    const float* xr1 = x + ib1 + lane;
    float* outp0 = out + ib0;
    float* outp1 = out + ib1;

    const int bidx = 136 * q + 8 * u8 + 8 * gg;   // B-read base (elems); +16*t, t=0..5
    unsigned short* rbA0 = &rowbuf[wv][0][0][0];  // img0 phase0
    unsigned short* rbA1 = &rowbuf[wv][0][1][0];  // img0 phase1
    unsigned short* rbB0 = &rowbuf[wv][1][0][0];  // img1 phase0
    unsigned short* rbB1 = &rowbuf[wv][1][1][0];  // img1 phase1
    const int wbase = lane + 25;                  // write elem = wbase + 135*qq

    f32x16 acc[2][2][2] = {};                     // [img][mtile][ntile]
    const int abase = gg * 1024 + n32 * 8;        // + row*8 + ks*2048

    auto compute = [&](const unsigned short* __restrict__ rb0,
                       const unsigned short* __restrict__ rb1, int r) {
        const bool t0 = (r <= 56);
        const bool t1 = (r >= 7);
        bf16x8 A0[4], A1[4];
        if (t0) {
            const int ai = abase + (63 - r) * 8;
            #pragma unroll
            for (int ks = 0; ks < 4; ++ks) A0[ks] = *(const bf16x8*)&wlds[ai + ks * 2048];
        }
        if (t1) {
            const int ai = abase + (95 - r) * 8;
            #pragma unroll
            for (int ks = 0; ks < 4; ++ks) A1[ks] = *(const bf16x8*)&wlds[ai + ks * 2048];
        }
        const unsigned short* rbs[2] = { rb0, rb1 };
        #pragma unroll
        for (int img = 0; img < 2; ++img) {
            bf16x8 d[6];
            #pragma unroll
            for (int t = 0; t < 6; ++t) d[t] = *(const bf16x8*)&rbs[img][bidx + 16 * t];
            if (t0) {
                #pragma unroll
                for (int ks = 0; ks < 4; ++ks) {
                    acc[img][0][0] = __builtin_amdgcn_mfma_f32_32x32x16_bf16(A0[ks], d[ks],     acc[img][0][0], 0, 0, 0);
                    acc[img][0][1] = __builtin_amdgcn_mfma_f32_32x32x16_bf16(A0[ks], d[ks + 2], acc[img][0][1], 0, 0, 0);
                }
            }
            if (t1) {
                #pragma unroll
                for (int ks = 0; ks < 4; ++ks) {
                    acc[img][1][0] = __builtin_amdgcn_mfma_f32_32x32x16_bf16(A1[ks], d[ks],     acc[img][1][0], 0, 0, 0);
                    acc[img][1][1] = __builtin_amdgcn_mfma_f32_32x32x16_bf16(A1[ks], d[ks + 2], acc[img][1][1], 0, 0, 0);
                }
            }
        }
    };

    // prologue: row 0 -> phase-0 bufs, prefetch row 1
    float xv0 = xr0[0], xv1 = xr1[0];
    {
        const unsigned short b0w = f2bf_bits(xv0), b1w = f2bf_bits(xv1);
        #pragma unroll
        for (int qq = 0; qq < 8; ++qq) {
            rbA0[wbase + 135 * qq] = b0w;
            rbB0[wbase + 135 * qq] = b1w;
        }
    }
    xv0 = xr0[64]; xv1 = xr1[64];

    #pragma unroll 1
    for (int rr = 0; rr < 64; rr += 2) {
        // ---- phase 0: write row rr+1 -> phase-1 bufs, compute row rr from phase-0 ----
        {
            const unsigned short b0w = f2bf_bits(xv0), b1w = f2bf_bits(xv1);
            #pragma unroll
            for (int qq = 0; qq < 8; ++qq) {
                rbA1[wbase + 135 * qq] = b0w;
                rbB1[wbase + 135 * qq] = b1w;
            }
            if (rr + 2 < 64) { xv0 = xr0[(rr + 2) * 64]; xv1 = xr1[(rr + 2) * 64]; }
            compute(rbA0, rbB0, rr);
        }
        // ---- phase 1: write row rr+2 -> phase-0 bufs, compute row rr+1 from phase-1 ----
        {
            if (rr + 2 < 64) {
                const unsigned short b0w = f2bf_bits(xv0), b1w = f2bf_bits(xv1);
                #pragma unroll
                for (int qq = 0; qq < 8; ++qq) {
                    rbA0[wbase + 135 * qq] = b0w;
                    rbB0[wbase + 135 * qq] = b1w;
                }
                if (rr + 3 < 64) { xv0 = xr0[(rr + 3) * 64]; xv1 = xr1[(rr + 3) * 64]; }
            }
            compute(rbA1, rbB1, rr + 1);
        }
    }

    // ---- epilogue: D layout (32x32): col = lane&31, row = (v&3) + 8*(v>>2) + 4*(lane>>5) ----
    #pragma unroll
    for (int v = 0; v < 16; ++v) {
        const int ho = (v & 3) + 8 * (v >> 2) + 4 * gg;
        outp0[ho * 64 + n32]             = acc[0][0][0][v];
        outp0[ho * 64 + n32 + 32]        = acc[0][0][1][v];
        outp0[(ho + 32) * 64 + n32]      = acc[0][1][0][v];
        outp0[(ho + 32) * 64 + n32 + 32] = acc[0][1][1][v];
        outp1[ho * 64 + n32]             = acc[1][0][0][v];
        outp1[ho * 64 + n32 + 32]        = acc[1][0][1][v];
        outp1[(ho + 32) * 64 + n32]      = acc[1][1][0][v];
        outp1[(ho + 32) * 64 + n32 + 32] = acc[1][1][1][v];
    }
}

extern "C" void kernel_launch(void* const* d_in, const int* in_sizes, int n_in,
                              void* d_out, int out_size, void* d_ws, size_t ws_size,
                              hipStream_t stream) {
    (void)in_sizes; (void)n_in; (void)d_ws; (void)ws_size; (void)out_size;
    const float* x   = (const float*)d_in[0];
    const float* w5  = (const float*)d_in[1];
    const float* w51 = (const float*)d_in[2];
    float* out = (float*)d_out;
    dim3 grid(192 * 4), block(256);
    hipLaunchKernelGGL(dw5_51_kernel, grid, block, 0, stream, x, w5, w51, out);
}